// Round 1
// baseline (737.107 us; speedup 1.0000x reference)
//
#include <hip/hip_runtime.h>
#include <hip/hip_bf16.h>
#include <string.h>

#define N_USERS 30000
#define N_NODES 100000
#define DIM 64
#define N_EDGES 1600000
#define E_PAD (N_EDGES + 3 * N_NODES)   // rows padded to multiple of 4 edges
#define SCAN_ELEMS 2048
#define SCAN_NB ((N_NODES + SCAN_ELEMS - 1) / SCAN_ELEMS)  // 49
#define ROWS_PER_BUCK 128
#define NBUCK ((N_NODES + ROWS_PER_BUCK - 1) / ROWS_PER_BUCK)  // 782

typedef __hip_bfloat16 bf16;
typedef __attribute__((ext_vector_type(8))) short short8;   // 8 bf16 = 4 VGPRs
typedef __attribute__((ext_vector_type(4))) float floatx4;  // MFMA accumulator

__device__ __forceinline__ float b2f(bf16 v) { return __bfloat162float(v); }
__device__ __forceinline__ bf16 f2b(float v) { return __float2bfloat16(v); }
__device__ __forceinline__ unsigned short fbits(float v) {
    bf16 b = f2b(v); unsigned short u; memcpy(&u, &b, 2); return u;
}
__device__ __forceinline__ float ubf(unsigned u) {
    return __uint_as_float(u << 16);
}

// dtype-flexible load/store: f32 flag selects float* vs bf16* interpretation
__device__ __forceinline__ float ld(const void* p, int i, int f32) {
    return f32 ? ((const float*)p)[i] : b2f(((const bf16*)p)[i]);
}
__device__ __forceinline__ void st(void* p, int i, float v, int f32) {
    if (f32) ((float*)p)[i] = v; else ((bf16*)p)[i] = f2b(v);
}

// ---------------------------------------------------------------------------
// Detect fp32 vs bf16 per tensor (bf16 bits read as fp32 -> huge exponents).
// flags: 0=embeddings/out world, 1=entity, 2=vals, 3=weights
// ---------------------------------------------------------------------------
__global__ void k_detect(const void* user, const void* ent, const void* vals,
                         const void* W, int* flags) {
    if (threadIdx.x == 0 && blockIdx.x == 0) {
        const void* ps[4] = { user, ent, vals, W };
        for (int t = 0; t < 4; ++t) {
            const float* f = (const float*)ps[t];
            int ok = 0;
            for (int i = 0; i < 32; ++i) {
                float v = f[i];
                if (v == v && fabsf(v) <= 1e4f) ok++;
            }
            flags[t] = (ok >= 16) ? 1 : 0;
        }
    }
}

__global__ void k_zero(int* __restrict__ cnt) {
    int i = blockIdx.x * blockDim.x + threadIdx.x;
    if (i <= N_NODES) cnt[i] = 0;
}

__global__ void k_hist(const int* __restrict__ rows, int* __restrict__ cnt) {
    int e = (blockIdx.x * blockDim.x + threadIdx.x) * 4;
    if (e >= N_EDGES) return;
    int4 r = *(const int4*)&rows[e];
    atomicAdd(&cnt[r.x], 1);
    atomicAdd(&cnt[r.y], 1);
    atomicAdd(&cnt[r.z], 1);
    atomicAdd(&cnt[r.w], 1);
}

// exclusive scan of counts padded to multiple of 4 (in-place)
__global__ __launch_bounds__(256) void k_scan1(int* __restrict__ cnt,
                                               int* __restrict__ partials) {
    __shared__ int lds[256];
    int t = threadIdx.x;
    int base = blockIdx.x * SCAN_ELEMS + t * 8;
    int local[8];
    int sum = 0;
#pragma unroll
    for (int i = 0; i < 8; ++i) {
        int idx = base + i;
        int v = (idx < N_NODES) ? ((cnt[idx] + 3) & ~3) : 0;  // pad to mult of 4
        local[i] = sum;
        sum += v;
    }
    lds[t] = sum;
    __syncthreads();
    for (int off = 1; off < 256; off <<= 1) {
        int v = (t >= off) ? lds[t - off] : 0;
        __syncthreads();
        lds[t] += v;
        __syncthreads();
    }
    int texcl = (t == 0) ? 0 : lds[t - 1];
#pragma unroll
    for (int i = 0; i < 8; ++i) {
        int idx = base + i;
        if (idx < N_NODES) cnt[idx] = texcl + local[i];
    }
    if (t == 255) partials[blockIdx.x] = lds[255];
}

__global__ void k_scan2(int* __restrict__ partials) {
    int l = threadIdx.x;
    int v = (l < SCAN_NB) ? partials[l] : 0;
    int inc = v;
    for (int off = 1; off < 64; off <<= 1) {
        int u = __shfl_up(inc, off, 64);
        if (l >= off) inc += u;
    }
    if (l < SCAN_NB) partials[l] = inc - v;   // exclusive
    if (l == 63) partials[SCAN_NB] = inc;     // total (padded)
}

// finalize row_start; also init per-bucket cursors (bucket b starts at
// row_start[b*128] since offsets are already padded/cumulative)
__global__ void k_scan3(int* __restrict__ cnt, int* __restrict__ bcur,
                        const int* __restrict__ partials) {
    int i = blockIdx.x * blockDim.x + threadIdx.x;
    if (i < N_NODES) {
        int v = cnt[i] + partials[i / SCAN_ELEMS];
        cnt[i] = v;
        if ((i & (ROWS_PER_BUCK - 1)) == 0) bcur[i >> 7] = v;
    } else if (i == N_NODES) {
        cnt[N_NODES] = partials[SCAN_NB];
    }
}

// ---------------------------------------------------------------------------
// Pass 1: scatter edges into BUCKET order (bucket = row>>7, 782 buckets).
// Each bucket's cursor advances sequentially -> L2 lines fill completely
// before writeback (write traffic ~13 MB instead of 99 MB of partial-line
// writebacks). row-within-bucket (7 bits) packed into bits 17..23 of .x.
// ---------------------------------------------------------------------------
__global__ void k_bscatter(const int* __restrict__ rows, const int* __restrict__ cols,
                           const void* __restrict__ vals, int* __restrict__ bcur,
                           int2* __restrict__ bpack, const int* __restrict__ flags) {
    int e = blockIdx.x * blockDim.x + threadIdx.x;
    if (e >= N_EDGES) return;
    int fv = flags[2];
    int r = rows[e];
    int pos = atomicAdd(&bcur[r >> 7], 1);
    bpack[pos] = make_int2(cols[e] | ((r & (ROWS_PER_BUCK - 1)) << 17),
                           __float_as_int(ld(vals, e, fv)));
}

// ---------------------------------------------------------------------------
// Pass 2: one block per bucket. Read bucket range sequentially, place each
// edge at its final CSR slot via LDS row cursors (no global atomics); the
// destination window per block is ~16 KB -> full-line write combining.
// Padding of each row's <=3 tail slots folded in (replaces k_pad).
// ---------------------------------------------------------------------------
__global__ __launch_bounds__(256) void k_place(const int* __restrict__ row_start,
                                               const int* __restrict__ bcur,
                                               const int2* __restrict__ bpack,
                                               int2* __restrict__ epack) {
    __shared__ int cur[ROWS_PER_BUCK];
    int b = blockIdx.x, t = threadIdx.x;
    int rbase = b << 7;
    int nrows = min(ROWS_PER_BUCK, N_NODES - rbase);
    if (t < nrows) cur[t] = row_start[rbase + t];
    __syncthreads();
    int start = row_start[rbase];
    int end = bcur[b];            // final fill position after k_bscatter
    for (int i = start + t; i < end; i += 256) {
        int2 p = bpack[i];
        int r = ((unsigned)p.x) >> 17;
        int pos = atomicAdd(&cur[r], 1);
        epack[pos] = make_int2(p.x & 0x1FFFF, p.y);
    }
    __syncthreads();
    for (int r = t; r < nrows; r += 256) {
        int pos = cur[r], pend = row_start[rbase + r + 1];
        for (; pos < pend; ++pos) epack[pos] = make_int2(0, 0);
    }
}

// ---------------------------------------------------------------------------
// out[:, :64] = concat(user, entity); xb0 = bf16 gather table of ego0
// ---------------------------------------------------------------------------
__global__ void k_init(const void* __restrict__ user, const void* __restrict__ ent,
                       void* __restrict__ out, bf16* __restrict__ xb0,
                       const int* __restrict__ flags) {
    int i = blockIdx.x * blockDim.x + threadIdx.x;
    if (i >= N_NODES * DIM) return;
    int fo = flags[0], fe = flags[1];
    int n = i >> 6, d = i & 63;
    float v = (n < N_USERS) ? ld(user, i, fo) : ld(ent, i - N_USERS * DIM, fe);
    st(out, n * 160 + d, v, fo);
    xb0[i] = f2b(v);
}

// ---------------------------------------------------------------------------
// Gather phase (shared by both layers): wave owns 4 rows, lane = dim.
// Branchless body: 16 gathers/iter (4 rows x 4 edges), masked cols/vals;
// next edge-packs preloaded between gather issue and FMA consumption.
// Macro locals are namespaced eA/eB/ej/ev to avoid collisions.
// ---------------------------------------------------------------------------
#define GATHER_ROW_DECL(r) \
    int ej##r = rs[r], eend##r = rs[r + 1]; \
    bool ev##r = ej##r < eend##r; \
    int4 eA##r = {0,0,0,0}, eB##r = {0,0,0,0}; \
    if (ev##r) { eA##r = ep4[ej##r >> 1]; eB##r = ep4[(ej##r >> 1) + 1]; } \
    float ea##r = 0.f;

#define GATHER_EXTRACT(r) \
    int ec##r##0 = ev##r ? eA##r.x : 0, ec##r##1 = ev##r ? eA##r.z : 0; \
    int ec##r##2 = ev##r ? eB##r.x : 0, ec##r##3 = ev##r ? eB##r.z : 0; \
    float ew##r##0 = ev##r ? __int_as_float(eA##r.y) : 0.f; \
    float ew##r##1 = ev##r ? __int_as_float(eA##r.w) : 0.f; \
    float ew##r##2 = ev##r ? __int_as_float(eB##r.y) : 0.f; \
    float ew##r##3 = ev##r ? __int_as_float(eB##r.w) : 0.f;

#define GATHER_ISSUE(r) \
    unsigned eg##r##0 = xu[ec##r##0 * 64 + lane]; \
    unsigned eg##r##1 = xu[ec##r##1 * 64 + lane]; \
    unsigned eg##r##2 = xu[ec##r##2 * 64 + lane]; \
    unsigned eg##r##3 = xu[ec##r##3 * 64 + lane];

#define GATHER_ADVANCE(r) \
    ej##r += ev##r ? 4 : 0; \
    ev##r = ej##r < eend##r; \
    if (ev##r) { eA##r = ep4[ej##r >> 1]; eB##r = ep4[(ej##r >> 1) + 1]; }

#define GATHER_FMA(r) \
    ea##r += ew##r##0 * ubf(eg##r##0); \
    ea##r += ew##r##1 * ubf(eg##r##1); \
    ea##r += ew##r##2 * ubf(eg##r##2); \
    ea##r += ew##r##3 * ubf(eg##r##3);

#define GATHER_BODY \
    GATHER_ROW_DECL(0) GATHER_ROW_DECL(1) GATHER_ROW_DECL(2) GATHER_ROW_DECL(3) \
    while (ev0 | ev1 | ev2 | ev3) { \
        GATHER_EXTRACT(0) GATHER_EXTRACT(1) GATHER_EXTRACT(2) GATHER_EXTRACT(3) \
        GATHER_ISSUE(0) GATHER_ISSUE(1) GATHER_ISSUE(2) GATHER_ISSUE(3) \
        GATHER_ADVANCE(0) GATHER_ADVANCE(1) GATHER_ADVANCE(2) GATHER_ADVANCE(3) \
        GATHER_FMA(0) GATHER_FMA(1) GATHER_FMA(2) GATHER_FMA(3) \
    }

// ---------------------------------------------------------------------------
// Fused layer 1 (64->64): 16 rows/block, 4 waves. MFMA combine, C/D layout
// col=lane&15, row=(lane>>4)*4+reg. Wave w -> output cols 16w..16w+15.
// ---------------------------------------------------------------------------
__global__ __launch_bounds__(256) void k_layer1(
    const void* __restrict__ W1, const void* __restrict__ b1,
    const void* __restrict__ W2, const void* __restrict__ b2,
    void* __restrict__ out, const int* __restrict__ row_start,
    const int2* __restrict__ epack, const bf16* __restrict__ xt,
    bf16* __restrict__ xn, const int* __restrict__ flags) {
    __shared__ __align__(16) unsigned short hp_lds[16][72];
    __shared__ __align__(16) unsigned short hm_lds[16][72];
    __shared__ __align__(16) float ssq_lds[16][4];
    int t = threadIdx.x, lane = t & 63, w = t >> 6;
    int sub = lane & 15, quad = lane >> 4;
    int fo = flags[0], fw = flags[3];
    int rbase = blockIdx.x * 16 + w * 4;
    const unsigned short* xu = (const unsigned short*)xt;
    const int4* ep4 = (const int4*)epack;

    int rs[5];
#pragma unroll
    for (int r = 0; r < 5; ++r) rs[r] = row_start[rbase + r];
    GATHER_BODY
    {
        float s[4] = { ea0, ea1, ea2, ea3 };
#pragma unroll
        for (int r = 0; r < 4; ++r) {
            float h = ld(out, (rbase + r) * 160 + lane, fo);
            hp_lds[w * 4 + r][lane] = fbits(h + s[r]);
            hm_lds[w * 4 + r][lane] = fbits(h * s[r]);
        }
    }
    __syncthreads();

    // A fragments: A[m=sub][k=quad*8+j] (+32 for second k-half)
    short8 Ap0 = *(const short8*)((const char*)hp_lds + sub * 144 + quad * 16);
    short8 Ap1 = *(const short8*)((const char*)hp_lds + sub * 144 + 64 + quad * 16);
    short8 Am0 = *(const short8*)((const char*)hm_lds + sub * 144 + quad * 16);
    short8 Am1 = *(const short8*)((const char*)hm_lds + sub * 144 + 64 + quad * 16);

    // B fragments: B[k=quad*8+j][n=wbase+sub], W row-major [64][64]
    int wbase = w * 16;
    short8 Bw10, Bw11, Bw20, Bw21;
    float bias1, bias2;
    if (fw) {
        const float* w1 = (const float*)W1;
        const float* w2 = (const float*)W2;
#pragma unroll
        for (int j = 0; j < 8; ++j) {
            int k0 = quad * 8 + j;
            Bw10[j] = (short)fbits(w1[k0 * 64 + wbase + sub]);
            Bw11[j] = (short)fbits(w1[(k0 + 32) * 64 + wbase + sub]);
            Bw20[j] = (short)fbits(w2[k0 * 64 + wbase + sub]);
            Bw21[j] = (short)fbits(w2[(k0 + 32) * 64 + wbase + sub]);
        }
        bias1 = ((const float*)b1)[wbase + sub];
        bias2 = ((const float*)b2)[wbase + sub];
    } else {
        const unsigned short* w1 = (const unsigned short*)W1;
        const unsigned short* w2 = (const unsigned short*)W2;
#pragma unroll
        for (int j = 0; j < 8; ++j) {
            int k0 = quad * 8 + j;
            Bw10[j] = (short)w1[k0 * 64 + wbase + sub];
            Bw11[j] = (short)w1[(k0 + 32) * 64 + wbase + sub];
            Bw20[j] = (short)w2[k0 * 64 + wbase + sub];
            Bw21[j] = (short)w2[(k0 + 32) * 64 + wbase + sub];
        }
        bias1 = b2f(((const bf16*)b1)[wbase + sub]);
        bias2 = b2f(((const bf16*)b2)[wbase + sub]);
    }

    floatx4 c1; c1[0] = bias1; c1[1] = bias1; c1[2] = bias1; c1[3] = bias1;
    floatx4 c2; c2[0] = bias2; c2[1] = bias2; c2[2] = bias2; c2[3] = bias2;
    c1 = __builtin_amdgcn_mfma_f32_16x16x32_bf16(Ap0, Bw10, c1, 0, 0, 0);
    c1 = __builtin_amdgcn_mfma_f32_16x16x32_bf16(Ap1, Bw11, c1, 0, 0, 0);
    c2 = __builtin_amdgcn_mfma_f32_16x16x32_bf16(Am0, Bw20, c2, 0, 0, 0);
    c2 = __builtin_amdgcn_mfma_f32_16x16x32_bf16(Am1, Bw21, c2, 0, 0, 0);

    float v[4], sp[4];
#pragma unroll
    for (int r = 0; r < 4; ++r) {
        float s1 = c1[r], s2 = c2[r];
        s1 = s1 > 0.f ? s1 : 0.01f * s1;
        s2 = s2 > 0.f ? s2 : 0.01f * s2;
        v[r] = s1 + s2;
        float sq = v[r] * v[r];
        sq += __shfl_xor(sq, 1, 64);
        sq += __shfl_xor(sq, 2, 64);
        sq += __shfl_xor(sq, 4, 64);
        sq += __shfl_xor(sq, 8, 64);
        sp[r] = sq;
    }
    if (sub == 0) {
#pragma unroll
        for (int r = 0; r < 4; ++r) ssq_lds[quad * 4 + r][w] = sp[r];
    }
    __syncthreads();
#pragma unroll
    for (int r = 0; r < 4; ++r) {
        int row = quad * 4 + r;
        floatx4 ps = *(const floatx4*)&ssq_lds[row][0];
        float ss = ps[0] + ps[1] + ps[2] + ps[3];
        float o = v[r] * (1.0f / fmaxf(sqrtf(ss), 1e-12f));
        int n = blockIdx.x * 16 + row;
        st(out, n * 160 + 64 + wbase + sub, o, fo);
        xn[n * 64 + wbase + sub] = f2b(o);
    }
}

// ---------------------------------------------------------------------------
// Fused layer 2 (64->32): same gather; waves 0,1 = sum path (W1), waves 2,3 =
// bi path (W2); cross-path add via LDS; l2norm over 32.
// ---------------------------------------------------------------------------
__global__ __launch_bounds__(256) void k_layer2(
    const void* __restrict__ W1, const void* __restrict__ b1,
    const void* __restrict__ W2, const void* __restrict__ b2,
    void* __restrict__ out, const int* __restrict__ row_start,
    const int2* __restrict__ epack, const bf16* __restrict__ xt,
    const int* __restrict__ flags) {
    __shared__ __align__(16) unsigned short hp_lds[16][72];
    __shared__ __align__(16) unsigned short hm_lds[16][72];
    __shared__ __align__(16) float bi_lds[16][32];
    __shared__ __align__(16) float ssq_lds[16][2];
    int t = threadIdx.x, lane = t & 63, w = t >> 6;
    int sub = lane & 15, quad = lane >> 4;
    int fo = flags[0], fw = flags[3];
    int rbase = blockIdx.x * 16 + w * 4;
    const unsigned short* xu = (const unsigned short*)xt;
    const int4* ep4 = (const int4*)epack;

    int rs[5];
#pragma unroll
    for (int r = 0; r < 5; ++r) rs[r] = row_start[rbase + r];
    GATHER_BODY
    {
        float s[4] = { ea0, ea1, ea2, ea3 };
#pragma unroll
        for (int r = 0; r < 4; ++r) {
            float h = ld(out, (rbase + r) * 160 + 64 + lane, fo);
            hp_lds[w * 4 + r][lane] = fbits(h + s[r]);
            hm_lds[w * 4 + r][lane] = fbits(h * s[r]);
        }
    }
    __syncthreads();

    int path = w >> 1;               // 0: sum(W1), 1: bi(W2)
    int nbase = (w & 1) * 16;        // col tile within 32
    const unsigned short(*hl)[72] = path ? hm_lds : hp_lds;
    short8 Af0 = *(const short8*)((const char*)hl + sub * 144 + quad * 16);
    short8 Af1 = *(const short8*)((const char*)hl + sub * 144 + 64 + quad * 16);

    const void* W = path ? W2 : W1;
    const void* bb = path ? b2 : b1;
    short8 Bf0, Bf1;
    float bias;
    if (fw) {
        const float* wp = (const float*)W;
#pragma unroll
        for (int j = 0; j < 8; ++j) {
            int k0 = quad * 8 + j;
            Bf0[j] = (short)fbits(wp[k0 * 32 + nbase + sub]);
            Bf1[j] = (short)fbits(wp[(k0 + 32) * 32 + nbase + sub]);
        }
        bias = ((const float*)bb)[nbase + sub];
    } else {
        const unsigned short* wp = (const unsigned short*)W;
#pragma unroll
        for (int j = 0; j < 8; ++j) {
            int k0 = quad * 8 + j;
            Bf0[j] = (short)wp[k0 * 32 + nbase + sub];
            Bf1[j] = (short)wp[(k0 + 32) * 32 + nbase + sub];
        }
        bias = b2f(((const bf16*)bb)[nbase + sub]);
    }

    floatx4 c; c[0] = bias; c[1] = bias; c[2] = bias; c[3] = bias;
    c = __builtin_amdgcn_mfma_f32_16x16x32_bf16(Af0, Bf0, c, 0, 0, 0);
    c = __builtin_amdgcn_mfma_f32_16x16x32_bf16(Af1, Bf1, c, 0, 0, 0);

    float T[4];
#pragma unroll
    for (int r = 0; r < 4; ++r) {
        float x = c[r];
        T[r] = x > 0.f ? x : 0.01f * x;
        if (path == 1) bi_lds[quad * 4 + r][nbase + sub] = T[r];
    }
    __syncthreads();

    float v[4], sp[4];
#pragma unroll
    for (int r = 0; r < 4; ++r) {
        v[r] = T[r] + bi_lds[quad * 4 + r][nbase + sub];
        float sq = v[r] * v[r];
        sq += __shfl_xor(sq, 1, 64);
        sq += __shfl_xor(sq, 2, 64);
        sq += __shfl_xor(sq, 4, 64);
        sq += __shfl_xor(sq, 8, 64);
        sp[r] = sq;
    }
    if (path == 0 && sub == 0) {
#pragma unroll
        for (int r = 0; r < 4; ++r) ssq_lds[quad * 4 + r][w & 1] = sp[r];
    }
    __syncthreads();
    if (path == 0) {
#pragma unroll
        for (int r = 0; r < 4; ++r) {
            int row = quad * 4 + r;
            float ss = ssq_lds[row][0] + ssq_lds[row][1];
            float o = v[r] * (1.0f / fmaxf(sqrtf(ss), 1e-12f));
            int n = blockIdx.x * 16 + row;
            st(out, n * 160 + 128 + nbase + sub, o, fo);
        }
    }
}

extern "C" void kernel_launch(void* const* d_in, const int* in_sizes, int n_in,
                              void* d_out, int out_size, void* d_ws, size_t ws_size,
                              hipStream_t stream) {
    const void* user = d_in[0];
    const void* ent  = d_in[1];
    const void* vals = d_in[2];
    const void* W1_1 = d_in[3];
    const void* b1_1 = d_in[4];
    const void* W2_1 = d_in[5];
    const void* b2_1 = d_in[6];
    const void* W1_2 = d_in[7];
    const void* b1_2 = d_in[8];
    const void* W2_2 = d_in[9];
    const void* b2_2 = d_in[10];
    const int* rows  = (const int*)d_in[11];
    const int* cols  = (const int*)d_in[12];

    // ws: [flags][partials][bcur][row_start N+1][epack E_PAD int2][xb0][xb1]
    // bpack (bucket-ordered edges) aliases xb0/xb1 (dead until k_init)
    char* w = (char*)d_ws;
    int* flags     = (int*)w;  w += 256;
    int* partials  = (int*)w;  w += 256;
    int* bcur      = (int*)w;  w += 4096;                   // NBUCK=782 ints
    int* row_start = (int*)w;  w += 400128;                 // (N+1)*4 padded
    int2* epack    = (int2*)w; w += (size_t)E_PAD * 8;
    bf16* xb0      = (bf16*)w; w += (size_t)N_NODES * DIM * 2;
    bf16* xb1      = (bf16*)w;
    int2* bpack    = (int2*)xb0;  // 15.2 MB <= 25.6 MB of xb0+xb1; dead before k_init

    k_detect<<<1, 64, 0, stream>>>(user, ent, vals, W1_1, flags);
    k_zero<<<(N_NODES + 256) / 256, 256, 0, stream>>>(row_start);
    k_hist<<<(N_EDGES / 4 + 255) / 256, 256, 0, stream>>>(rows, row_start);
    k_scan1<<<SCAN_NB, 256, 0, stream>>>(row_start, partials);
    k_scan2<<<1, 64, 0, stream>>>(partials);
    k_scan3<<<(N_NODES + 256) / 256, 256, 0, stream>>>(row_start, bcur, partials);
    k_bscatter<<<(N_EDGES + 255) / 256, 256, 0, stream>>>(rows, cols, vals, bcur, bpack, flags);
    k_place<<<NBUCK, 256, 0, stream>>>(row_start, bcur, bpack, epack);
    k_init<<<(N_NODES * DIM + 255) / 256, 256, 0, stream>>>(user, ent, d_out, xb0, flags);
    k_layer1<<<N_NODES / 16, 256, 0, stream>>>(W1_1, b1_1, W2_1, b2_1, d_out, row_start, epack, xb0, xb1, flags);
    k_layer2<<<N_NODES / 16, 256, 0, stream>>>(W1_2, b1_2, W2_2, b2_2, d_out, row_start, epack, xb1, flags);
}

// Round 2
// 331.811 us; speedup vs baseline: 2.2215x; 2.2215x over previous
//
#include <hip/hip_runtime.h>
#include <hip/hip_bf16.h>
#include <string.h>

#define N_USERS 30000
#define N_NODES 100000
#define DIM 64
#define N_EDGES 1600000
#define ROWS_PER_BUCK 256
#define NB ((N_NODES + ROWS_PER_BUCK - 1) / ROWS_PER_BUCK)   // 391 buckets
#define CHUNK 8192
#define NBLK_B ((N_EDGES + CHUNK - 1) / CHUNK)               // 196 blocks
#define E_ALLOC 1901464   // N_EDGES + NB*(3*ROWS_PER_BUCK+3) rounded to 4
#define STAGE_CAP 5120    // LDS-staged edges per bucket (mean 4092, +16 sigma)

typedef __hip_bfloat16 bf16;
typedef __attribute__((ext_vector_type(8))) short short8;   // 8 bf16 = 4 VGPRs
typedef __attribute__((ext_vector_type(4))) float floatx4;  // MFMA accumulator

__device__ __forceinline__ float b2f(bf16 v) { return __bfloat162float(v); }
__device__ __forceinline__ bf16 f2b(float v) { return __float2bfloat16(v); }
__device__ __forceinline__ unsigned short fbits(float v) {
    bf16 b = f2b(v); unsigned short u; memcpy(&u, &b, 2); return u;
}
__device__ __forceinline__ float ubf(unsigned u) {
    return __uint_as_float(u << 16);
}

// dtype-flexible load/store: f32 flag selects float* vs bf16* interpretation
__device__ __forceinline__ float ld(const void* p, int i, int f32) {
    return f32 ? ((const float*)p)[i] : b2f(((const bf16*)p)[i]);
}
__device__ __forceinline__ void st(void* p, int i, float v, int f32) {
    if (f32) ((float*)p)[i] = v; else ((bf16*)p)[i] = f2b(v);
}

// ---------------------------------------------------------------------------
// Detect fp32 vs bf16 per tensor; also zero the per-bucket size array.
// flags: 0=embeddings/out world, 1=entity, 2=vals, 3=weights
// ---------------------------------------------------------------------------
__global__ void k_detect(const void* user, const void* ent, const void* vals,
                         const void* W, int* flags, int* bsize) {
    int t = threadIdx.x;
    for (int i = t; i < NB; i += 64) bsize[i] = 0;
    if (t == 0) {
        const void* ps[4] = { user, ent, vals, W };
        for (int k = 0; k < 4; ++k) {
            const float* f = (const float*)ps[k];
            int ok = 0;
            for (int i = 0; i < 32; ++i) {
                float v = f[i];
                if (v == v && fabsf(v) <= 1e4f) ok++;
            }
            flags[k] = (ok >= 16) ? 1 : 0;
        }
    }
}

// ---------------------------------------------------------------------------
// Pass A: per-block LDS histogram over NB coarse buckets (bucket = row>>8).
// Zero global atomic contention (LDS atomics only); per-bucket totals via
// 196*391 low-contention global atomics.
// ---------------------------------------------------------------------------
__global__ __launch_bounds__(256) void k_hista(const int* __restrict__ rows,
                                               int* __restrict__ cnt_table,
                                               int* __restrict__ bsize) {
    __shared__ int h[NB];
    int t = threadIdx.x, blk = blockIdx.x;
    for (int b = t; b < NB; b += 256) h[b] = 0;
    __syncthreads();
    int base = blk * CHUNK + t * 4;
#pragma unroll
    for (int it = 0; it < 8; ++it) {
        int e = base + it * 1024;
        if (e < N_EDGES) {
            int4 r = *(const int4*)&rows[e];
            atomicAdd(&h[r.x >> 8], 1);
            atomicAdd(&h[r.y >> 8], 1);
            atomicAdd(&h[r.z >> 8], 1);
            atomicAdd(&h[r.w >> 8], 1);
        }
    }
    __syncthreads();
    for (int b = t; b < NB; b += 256) {
        int v = h[b];
        cnt_table[blk * NB + b] = v;           // [block][bucket], contiguous write
        if (v) atomicAdd(&bsize[b], v);
    }
}

// exclusive scan of padded bucket allocations -> bbase[0..NB]
__global__ __launch_bounds__(512) void k_bscan(const int* __restrict__ bsize,
                                               int* __restrict__ bbase) {
    __shared__ int lds[512];
    int t = threadIdx.x;
    // alloc = round4(bsize) + 3*ROWS_PER_BUCK (worst-case per-row padding)
    int v = (t < NB) ? (((bsize[t] + 3) & ~3) + 3 * ROWS_PER_BUCK) : 0;
    lds[t] = v;
    __syncthreads();
    for (int off = 1; off < 512; off <<= 1) {
        int u = (t >= off) ? lds[t - off] : 0;
        __syncthreads();
        lds[t] += u;
        __syncthreads();
    }
    if (t <= NB) bbase[t] = (t == 0) ? 0 : lds[t - 1];
}

// per-bucket scan over blocks: cnt_table[blk][b] -> bbase[b] + excl prefix
__global__ __launch_bounds__(256) void k_bscan2(int* __restrict__ cnt_table,
                                                const int* __restrict__ bbase) {
    __shared__ int lds[256];
    int t = threadIdx.x, b = blockIdx.x;
    int v = (t < NBLK_B) ? cnt_table[t * NB + b] : 0;
    lds[t] = v;
    __syncthreads();
    for (int off = 1; off < 256; off <<= 1) {
        int u = (t >= off) ? lds[t - off] : 0;
        __syncthreads();
        lds[t] += u;
        __syncthreads();
    }
    if (t < NBLK_B) cnt_table[t * NB + b] = bbase[b] + lds[t] - v;  // exclusive
}

// ---------------------------------------------------------------------------
// Pass B: stable-ish scatter into bucket order. Each block owns exact
// pre-reserved sub-regions per bucket (from cnt_table), cursors live in LDS
// -> zero global atomics; writes are contiguous runs per (block,bucket).
// Payload: col(17b) | row-in-bucket(8b)<<17, val bits.
// ---------------------------------------------------------------------------
__global__ __launch_bounds__(256) void k_bscatter2(
    const int* __restrict__ rows, const int* __restrict__ cols,
    const void* __restrict__ vals, const int* __restrict__ cnt_table,
    int2* __restrict__ bpack, const int* __restrict__ flags) {
    __shared__ int cur[NB];
    int t = threadIdx.x, blk = blockIdx.x;
    int fv = flags[2];
    for (int b = t; b < NB; b += 256) cur[b] = cnt_table[blk * NB + b];
    __syncthreads();
    int base = blk * CHUNK + t * 4;
#pragma unroll
    for (int it = 0; it < 8; ++it) {
        int e = base + it * 1024;
        if (e < N_EDGES) {
            int4 r = *(const int4*)&rows[e];
            int4 c = *(const int4*)&cols[e];
            float v0, v1, v2, v3;
            if (fv) {
                float4 vv = *(const float4*)((const float*)vals + e);
                v0 = vv.x; v1 = vv.y; v2 = vv.z; v3 = vv.w;
            } else {
                const bf16* bp = (const bf16*)vals + e;
                v0 = b2f(bp[0]); v1 = b2f(bp[1]); v2 = b2f(bp[2]); v3 = b2f(bp[3]);
            }
            int p0 = atomicAdd(&cur[r.x >> 8], 1);
            int p1 = atomicAdd(&cur[r.y >> 8], 1);
            int p2 = atomicAdd(&cur[r.z >> 8], 1);
            int p3 = atomicAdd(&cur[r.w >> 8], 1);
            bpack[p0] = make_int2(c.x | ((r.x & 255) << 17), __float_as_int(v0));
            bpack[p1] = make_int2(c.y | ((r.y & 255) << 17), __float_as_int(v1));
            bpack[p2] = make_int2(c.z | ((r.z & 255) << 17), __float_as_int(v2));
            bpack[p3] = make_int2(c.w | ((r.w & 255) << 17), __float_as_int(v3));
        }
    }
}

// ---------------------------------------------------------------------------
// Pass C: one block per bucket. Stage bucket edges in LDS + row histogram,
// scan padded counts -> row_start/row_end (replaces the old global
// hist+scan chain), place edges via LDS cursors into an L2-resident ~33 KB
// window (full-line write combining), pad each row's <=3 tail slots.
// Slack beyond row_end is never read (gather uses row_end), so no slack fill.
// ---------------------------------------------------------------------------
__global__ __launch_bounds__(256) void k_place2(
    const int* __restrict__ bsize, const int* __restrict__ bbase,
    const int2* __restrict__ bpack, int2* __restrict__ epack,
    int* __restrict__ row_start, int* __restrict__ row_end) {
    __shared__ __align__(16) int2 stage[STAGE_CAP];
    __shared__ int rcnt[ROWS_PER_BUCK];
    __shared__ int scan_lds[ROWS_PER_BUCK];
    __shared__ int rstart[ROWS_PER_BUCK];
    __shared__ int cur[ROWS_PER_BUCK];
    int t = threadIdx.x, b = blockIdx.x;
    int n = bsize[b];
    int gstart = bbase[b];
    rcnt[t] = 0;
    __syncthreads();
    for (int i = t; i < n; i += 256) {
        int2 p = bpack[gstart + i];
        if (i < STAGE_CAP) stage[i] = p;
        atomicAdd(&rcnt[(p.x >> 17) & 255], 1);
    }
    __syncthreads();
    int c = rcnt[t];
    int cp = (c + 3) & ~3;                 // pad row to multiple of 4 edges
    scan_lds[t] = cp;
    __syncthreads();
    for (int off = 1; off < 256; off <<= 1) {
        int u = (t >= off) ? scan_lds[t - off] : 0;
        __syncthreads();
        scan_lds[t] += u;
        __syncthreads();
    }
    int rs_ = gstart + scan_lds[t] - cp;   // exclusive
    rstart[t] = rs_;
    cur[t] = rs_;
    int node = b * ROWS_PER_BUCK + t;
    if (node < N_NODES) {
        row_start[node] = rs_;
        row_end[node] = rs_ + cp;
    }
    __syncthreads();
    for (int i = t; i < n; i += 256) {
        int2 p = (i < STAGE_CAP) ? stage[i] : bpack[gstart + i];
        int r = (p.x >> 17) & 255;
        int pos = atomicAdd(&cur[r], 1);
        epack[pos] = make_int2(p.x & 0x1FFFF, p.y);
    }
    __syncthreads();
    int pend = rstart[t] + cp;
    for (int pos = cur[t]; pos < pend; ++pos) epack[pos] = make_int2(0, 0);
}

// ---------------------------------------------------------------------------
// out[:, :64] = concat(user, entity); xb0 = bf16 gather table of ego0
// ---------------------------------------------------------------------------
__global__ void k_init(const void* __restrict__ user, const void* __restrict__ ent,
                       void* __restrict__ out, bf16* __restrict__ xb0,
                       const int* __restrict__ flags) {
    int i = blockIdx.x * blockDim.x + threadIdx.x;
    if (i >= N_NODES * DIM) return;
    int fo = flags[0], fe = flags[1];
    int n = i >> 6, d = i & 63;
    float v = (n < N_USERS) ? ld(user, i, fo) : ld(ent, i - N_USERS * DIM, fe);
    st(out, n * 160 + d, v, fo);
    xb0[i] = f2b(v);
}

// ---------------------------------------------------------------------------
// Gather phase (shared by both layers): wave owns 4 rows, lane = dim.
// Branchless body: 16 gathers/iter (4 rows x 4 edges), masked cols/vals;
// next edge-packs preloaded between gather issue and FMA consumption.
// Row ranges come from row_start[] (starts) and row_end[] (tight padded
// ends) so allocation slack between buckets is never read.
// ---------------------------------------------------------------------------
#define GATHER_ROW_DECL(r) \
    int ej##r = rs[r], eend##r = re[r]; \
    bool ev##r = ej##r < eend##r; \
    int4 eA##r = {0,0,0,0}, eB##r = {0,0,0,0}; \
    if (ev##r) { eA##r = ep4[ej##r >> 1]; eB##r = ep4[(ej##r >> 1) + 1]; } \
    float ea##r = 0.f;

#define GATHER_EXTRACT(r) \
    int ec##r##0 = ev##r ? eA##r.x : 0, ec##r##1 = ev##r ? eA##r.z : 0; \
    int ec##r##2 = ev##r ? eB##r.x : 0, ec##r##3 = ev##r ? eB##r.z : 0; \
    float ew##r##0 = ev##r ? __int_as_float(eA##r.y) : 0.f; \
    float ew##r##1 = ev##r ? __int_as_float(eA##r.w) : 0.f; \
    float ew##r##2 = ev##r ? __int_as_float(eB##r.y) : 0.f; \
    float ew##r##3 = ev##r ? __int_as_float(eB##r.w) : 0.f;

#define GATHER_ISSUE(r) \
    unsigned eg##r##0 = xu[ec##r##0 * 64 + lane]; \
    unsigned eg##r##1 = xu[ec##r##1 * 64 + lane]; \
    unsigned eg##r##2 = xu[ec##r##2 * 64 + lane]; \
    unsigned eg##r##3 = xu[ec##r##3 * 64 + lane];

#define GATHER_ADVANCE(r) \
    ej##r += ev##r ? 4 : 0; \
    ev##r = ej##r < eend##r; \
    if (ev##r) { eA##r = ep4[ej##r >> 1]; eB##r = ep4[(ej##r >> 1) + 1]; }

#define GATHER_FMA(r) \
    ea##r += ew##r##0 * ubf(eg##r##0); \
    ea##r += ew##r##1 * ubf(eg##r##1); \
    ea##r += ew##r##2 * ubf(eg##r##2); \
    ea##r += ew##r##3 * ubf(eg##r##3);

#define GATHER_BODY \
    GATHER_ROW_DECL(0) GATHER_ROW_DECL(1) GATHER_ROW_DECL(2) GATHER_ROW_DECL(3) \
    while (ev0 | ev1 | ev2 | ev3) { \
        GATHER_EXTRACT(0) GATHER_EXTRACT(1) GATHER_EXTRACT(2) GATHER_EXTRACT(3) \
        GATHER_ISSUE(0) GATHER_ISSUE(1) GATHER_ISSUE(2) GATHER_ISSUE(3) \
        GATHER_ADVANCE(0) GATHER_ADVANCE(1) GATHER_ADVANCE(2) GATHER_ADVANCE(3) \
        GATHER_FMA(0) GATHER_FMA(1) GATHER_FMA(2) GATHER_FMA(3) \
    }

// ---------------------------------------------------------------------------
// Fused layer 1 (64->64): 16 rows/block, 4 waves. MFMA combine, C/D layout
// col=lane&15, row=(lane>>4)*4+reg. Wave w -> output cols 16w..16w+15.
// ---------------------------------------------------------------------------
__global__ __launch_bounds__(256) void k_layer1(
    const void* __restrict__ W1, const void* __restrict__ b1,
    const void* __restrict__ W2, const void* __restrict__ b2,
    void* __restrict__ out, const int* __restrict__ row_start,
    const int* __restrict__ row_end,
    const int2* __restrict__ epack, const bf16* __restrict__ xt,
    bf16* __restrict__ xn, const int* __restrict__ flags) {
    __shared__ __align__(16) unsigned short hp_lds[16][72];
    __shared__ __align__(16) unsigned short hm_lds[16][72];
    __shared__ __align__(16) float ssq_lds[16][4];
    int t = threadIdx.x, lane = t & 63, w = t >> 6;
    int sub = lane & 15, quad = lane >> 4;
    int fo = flags[0], fw = flags[3];
    int rbase = blockIdx.x * 16 + w * 4;
    const unsigned short* xu = (const unsigned short*)xt;
    const int4* ep4 = (const int4*)epack;

    int4 rsv = *(const int4*)&row_start[rbase];
    int4 rev = *(const int4*)&row_end[rbase];
    int rs[4] = { rsv.x, rsv.y, rsv.z, rsv.w };
    int re[4] = { rev.x, rev.y, rev.z, rev.w };
    GATHER_BODY
    {
        float s[4] = { ea0, ea1, ea2, ea3 };
#pragma unroll
        for (int r = 0; r < 4; ++r) {
            float h = ld(out, (rbase + r) * 160 + lane, fo);
            hp_lds[w * 4 + r][lane] = fbits(h + s[r]);
            hm_lds[w * 4 + r][lane] = fbits(h * s[r]);
        }
    }
    __syncthreads();

    // A fragments: A[m=sub][k=quad*8+j] (+32 for second k-half)
    short8 Ap0 = *(const short8*)((const char*)hp_lds + sub * 144 + quad * 16);
    short8 Ap1 = *(const short8*)((const char*)hp_lds + sub * 144 + 64 + quad * 16);
    short8 Am0 = *(const short8*)((const char*)hm_lds + sub * 144 + quad * 16);
    short8 Am1 = *(const short8*)((const char*)hm_lds + sub * 144 + 64 + quad * 16);

    // B fragments: B[k=quad*8+j][n=wbase+sub], W row-major [64][64]
    int wbase = w * 16;
    short8 Bw10, Bw11, Bw20, Bw21;
    float bias1, bias2;
    if (fw) {
        const float* w1 = (const float*)W1;
        const float* w2 = (const float*)W2;
#pragma unroll
        for (int j = 0; j < 8; ++j) {
            int k0 = quad * 8 + j;
            Bw10[j] = (short)fbits(w1[k0 * 64 + wbase + sub]);
            Bw11[j] = (short)fbits(w1[(k0 + 32) * 64 + wbase + sub]);
            Bw20[j] = (short)fbits(w2[k0 * 64 + wbase + sub]);
            Bw21[j] = (short)fbits(w2[(k0 + 32) * 64 + wbase + sub]);
        }
        bias1 = ((const float*)b1)[wbase + sub];
        bias2 = ((const float*)b2)[wbase + sub];
    } else {
        const unsigned short* w1 = (const unsigned short*)W1;
        const unsigned short* w2 = (const unsigned short*)W2;
#pragma unroll
        for (int j = 0; j < 8; ++j) {
            int k0 = quad * 8 + j;
            Bw10[j] = (short)w1[k0 * 64 + wbase + sub];
            Bw11[j] = (short)w1[(k0 + 32) * 64 + wbase + sub];
            Bw20[j] = (short)w2[k0 * 64 + wbase + sub];
            Bw21[j] = (short)w2[(k0 + 32) * 64 + wbase + sub];
        }
        bias1 = b2f(((const bf16*)b1)[wbase + sub]);
        bias2 = b2f(((const bf16*)b2)[wbase + sub]);
    }

    floatx4 c1; c1[0] = bias1; c1[1] = bias1; c1[2] = bias1; c1[3] = bias1;
    floatx4 c2; c2[0] = bias2; c2[1] = bias2; c2[2] = bias2; c2[3] = bias2;
    c1 = __builtin_amdgcn_mfma_f32_16x16x32_bf16(Ap0, Bw10, c1, 0, 0, 0);
    c1 = __builtin_amdgcn_mfma_f32_16x16x32_bf16(Ap1, Bw11, c1, 0, 0, 0);
    c2 = __builtin_amdgcn_mfma_f32_16x16x32_bf16(Am0, Bw20, c2, 0, 0, 0);
    c2 = __builtin_amdgcn_mfma_f32_16x16x32_bf16(Am1, Bw21, c2, 0, 0, 0);

    float v[4], sp[4];
#pragma unroll
    for (int r = 0; r < 4; ++r) {
        float s1 = c1[r], s2 = c2[r];
        s1 = s1 > 0.f ? s1 : 0.01f * s1;
        s2 = s2 > 0.f ? s2 : 0.01f * s2;
        v[r] = s1 + s2;
        float sq = v[r] * v[r];
        sq += __shfl_xor(sq, 1, 64);
        sq += __shfl_xor(sq, 2, 64);
        sq += __shfl_xor(sq, 4, 64);
        sq += __shfl_xor(sq, 8, 64);
        sp[r] = sq;
    }
    if (sub == 0) {
#pragma unroll
        for (int r = 0; r < 4; ++r) ssq_lds[quad * 4 + r][w] = sp[r];
    }
    __syncthreads();
#pragma unroll
    for (int r = 0; r < 4; ++r) {
        int row = quad * 4 + r;
        floatx4 ps = *(const floatx4*)&ssq_lds[row][0];
        float ss = ps[0] + ps[1] + ps[2] + ps[3];
        float o = v[r] * (1.0f / fmaxf(sqrtf(ss), 1e-12f));
        int n = blockIdx.x * 16 + row;
        st(out, n * 160 + 64 + wbase + sub, o, fo);
        xn[n * 64 + wbase + sub] = f2b(o);
    }
}

// ---------------------------------------------------------------------------
// Fused layer 2 (64->32): same gather; waves 0,1 = sum path (W1), waves 2,3 =
// bi path (W2); cross-path add via LDS; l2norm over 32.
// ---------------------------------------------------------------------------
__global__ __launch_bounds__(256) void k_layer2(
    const void* __restrict__ W1, const void* __restrict__ b1,
    const void* __restrict__ W2, const void* __restrict__ b2,
    void* __restrict__ out, const int* __restrict__ row_start,
    const int* __restrict__ row_end,
    const int2* __restrict__ epack, const bf16* __restrict__ xt,
    const int* __restrict__ flags) {
    __shared__ __align__(16) unsigned short hp_lds[16][72];
    __shared__ __align__(16) unsigned short hm_lds[16][72];
    __shared__ __align__(16) float bi_lds[16][32];
    __shared__ __align__(16) float ssq_lds[16][2];
    int t = threadIdx.x, lane = t & 63, w = t >> 6;
    int sub = lane & 15, quad = lane >> 4;
    int fo = flags[0], fw = flags[3];
    int rbase = blockIdx.x * 16 + w * 4;
    const unsigned short* xu = (const unsigned short*)xt;
    const int4* ep4 = (const int4*)epack;

    int4 rsv = *(const int4*)&row_start[rbase];
    int4 rev = *(const int4*)&row_end[rbase];
    int rs[4] = { rsv.x, rsv.y, rsv.z, rsv.w };
    int re[4] = { rev.x, rev.y, rev.z, rev.w };
    GATHER_BODY
    {
        float s[4] = { ea0, ea1, ea2, ea3 };
#pragma unroll
        for (int r = 0; r < 4; ++r) {
            float h = ld(out, (rbase + r) * 160 + 64 + lane, fo);
            hp_lds[w * 4 + r][lane] = fbits(h + s[r]);
            hm_lds[w * 4 + r][lane] = fbits(h * s[r]);
        }
    }
    __syncthreads();

    int path = w >> 1;               // 0: sum(W1), 1: bi(W2)
    int nbase = (w & 1) * 16;        // col tile within 32
    const unsigned short(*hl)[72] = path ? hm_lds : hp_lds;
    short8 Af0 = *(const short8*)((const char*)hl + sub * 144 + quad * 16);
    short8 Af1 = *(const short8*)((const char*)hl + sub * 144 + 64 + quad * 16);

    const void* W = path ? W2 : W1;
    const void* bb = path ? b2 : b1;
    short8 Bf0, Bf1;
    float bias;
    if (fw) {
        const float* wp = (const float*)W;
#pragma unroll
        for (int j = 0; j < 8; ++j) {
            int k0 = quad * 8 + j;
            Bf0[j] = (short)fbits(wp[k0 * 32 + nbase + sub]);
            Bf1[j] = (short)fbits(wp[(k0 + 32) * 32 + nbase + sub]);
        }
        bias = ((const float*)bb)[nbase + sub];
    } else {
        const unsigned short* wp = (const unsigned short*)W;
#pragma unroll
        for (int j = 0; j < 8; ++j) {
            int k0 = quad * 8 + j;
            Bf0[j] = (short)wp[k0 * 32 + nbase + sub];
            Bf1[j] = (short)wp[(k0 + 32) * 32 + nbase + sub];
        }
        bias = b2f(((const bf16*)bb)[nbase + sub]);
    }

    floatx4 c; c[0] = bias; c[1] = bias; c[2] = bias; c[3] = bias;
    c = __builtin_amdgcn_mfma_f32_16x16x32_bf16(Af0, Bf0, c, 0, 0, 0);
    c = __builtin_amdgcn_mfma_f32_16x16x32_bf16(Af1, Bf1, c, 0, 0, 0);

    float T[4];
#pragma unroll
    for (int r = 0; r < 4; ++r) {
        float x = c[r];
        T[r] = x > 0.f ? x : 0.01f * x;
        if (path == 1) bi_lds[quad * 4 + r][nbase + sub] = T[r];
    }
    __syncthreads();

    float v[4], sp[4];
#pragma unroll
    for (int r = 0; r < 4; ++r) {
        v[r] = T[r] + bi_lds[quad * 4 + r][nbase + sub];
        float sq = v[r] * v[r];
        sq += __shfl_xor(sq, 1, 64);
        sq += __shfl_xor(sq, 2, 64);
        sq += __shfl_xor(sq, 4, 64);
        sq += __shfl_xor(sq, 8, 64);
        sp[r] = sq;
    }
    if (path == 0 && sub == 0) {
#pragma unroll
        for (int r = 0; r < 4; ++r) ssq_lds[quad * 4 + r][w & 1] = sp[r];
    }
    __syncthreads();
    if (path == 0) {
#pragma unroll
        for (int r = 0; r < 4; ++r) {
            int row = quad * 4 + r;
            float ss = ssq_lds[row][0] + ssq_lds[row][1];
            float o = v[r] * (1.0f / fmaxf(sqrtf(ss), 1e-12f));
            int n = blockIdx.x * 16 + row;
            st(out, n * 160 + 128 + nbase + sub, o, fo);
        }
    }
}

extern "C" void kernel_launch(void* const* d_in, const int* in_sizes, int n_in,
                              void* d_out, int out_size, void* d_ws, size_t ws_size,
                              hipStream_t stream) {
    const void* user = d_in[0];
    const void* ent  = d_in[1];
    const void* vals = d_in[2];
    const void* W1_1 = d_in[3];
    const void* b1_1 = d_in[4];
    const void* W2_1 = d_in[5];
    const void* b2_1 = d_in[6];
    const void* W1_2 = d_in[7];
    const void* b1_2 = d_in[8];
    const void* W2_2 = d_in[9];
    const void* b2_2 = d_in[10];
    const int* rows  = (const int*)d_in[11];
    const int* cols  = (const int*)d_in[12];

    // ws layout: [flags][bsize][bbase][row_start][row_end][epack][xb0][xb1]
    // cnt_table aliases epack (dead once k_bscatter2 completes, before k_place2
    // writes epack); bpack aliases xb0+xb1 (dead before k_init writes xb0).
    char* w = (char*)d_ws;
    int* flags     = (int*)w;  w += 256;
    int* bsize     = (int*)w;  w += 2048;                    // NB ints
    int* bbase     = (int*)w;  w += 2048;                    // NB+1 ints
    int* row_start = (int*)w;  w += 400128;                  // N_NODES ints padded
    int* row_end   = (int*)w;  w += 400128;
    int2* epack    = (int2*)w; w += (size_t)E_ALLOC * 8;
    bf16* xb0      = (bf16*)w; w += (size_t)N_NODES * DIM * 2;
    bf16* xb1      = (bf16*)w;
    int* cnt_table = (int*)epack;   // NBLK_B*NB ints = 307 KB << epack
    int2* bpack    = (int2*)xb0;    // 15.2 MB <= 25.6 MB of xb0+xb1

    k_detect<<<1, 64, 0, stream>>>(user, ent, vals, W1_1, flags, bsize);
    k_hista<<<NBLK_B, 256, 0, stream>>>(rows, cnt_table, bsize);
    k_bscan<<<1, 512, 0, stream>>>(bsize, bbase);
    k_bscan2<<<NB, 256, 0, stream>>>(cnt_table, bbase);
    k_bscatter2<<<NBLK_B, 256, 0, stream>>>(rows, cols, vals, cnt_table, bpack, flags);
    k_place2<<<NB, 256, 0, stream>>>(bsize, bbase, bpack, epack, row_start, row_end);
    k_init<<<(N_NODES * DIM + 255) / 256, 256, 0, stream>>>(user, ent, d_out, xb0, flags);
    k_layer1<<<N_NODES / 16, 256, 0, stream>>>(W1_1, b1_1, W2_1, b2_1, d_out, row_start, row_end, epack, xb0, xb1, flags);
    k_layer2<<<N_NODES / 16, 256, 0, stream>>>(W1_2, b1_2, W2_2, b2_2, d_out, row_start, row_end, epack, xb1, flags);
}

// Round 3
// 307.456 us; speedup vs baseline: 2.3974x; 1.0792x over previous
//
#include <hip/hip_runtime.h>
#include <hip/hip_bf16.h>
#include <string.h>

#define N_USERS 30000
#define N_NODES 100000
#define DIM 64
#define N_EDGES 1600000
#define ROWS_PER_BUCK 256
#define NB ((N_NODES + ROWS_PER_BUCK - 1) / ROWS_PER_BUCK)   // 391 buckets
#define CHUNK 8192
#define NBLK_B ((N_EDGES + CHUNK - 1) / CHUNK)               // 196 blocks
#define BUCK_SLACK 2048   // per-bucket alloc slack for group-max padding (5.5 sigma)
#define E_ALLOC (N_EDGES + NB * BUCK_SLACK)                  // 2,400,768 slots
#define STAGE_CAP 5120    // LDS-staged edges per bucket (mean 4092, +16 sigma)

typedef __hip_bfloat16 bf16;
typedef __attribute__((ext_vector_type(8))) short short8;   // 8 bf16 = 4 VGPRs
typedef __attribute__((ext_vector_type(4))) float floatx4;  // MFMA accumulator

__device__ __forceinline__ float b2f(bf16 v) { return __bfloat162float(v); }
__device__ __forceinline__ bf16 f2b(float v) { return __float2bfloat16(v); }
__device__ __forceinline__ unsigned short fbits(float v) {
    bf16 b = f2b(v); unsigned short u; memcpy(&u, &b, 2); return u;
}
__device__ __forceinline__ float ubf(unsigned u) {
    return __uint_as_float(u << 16);
}

// dtype-flexible load/store: f32 flag selects float* vs bf16* interpretation
__device__ __forceinline__ float ld(const void* p, int i, int f32) {
    return f32 ? ((const float*)p)[i] : b2f(((const bf16*)p)[i]);
}
__device__ __forceinline__ void st(void* p, int i, float v, int f32) {
    if (f32) ((float*)p)[i] = v; else ((bf16*)p)[i] = f2b(v);
}

// ---------------------------------------------------------------------------
// Detect fp32 vs bf16 per tensor (parallel: lane per element, shuffle-reduce;
// the old 1-thread version serialized 128 dependent global loads ~25us).
// flags: 0=embeddings/out world, 1=entity, 2=vals, 3=weights
// ---------------------------------------------------------------------------
__global__ void k_detect(const void* user, const void* ent, const void* vals,
                         const void* W, int* flags, int* bsize) {
    int t = threadIdx.x;   // 128 threads
    for (int i = t; i < NB; i += 128) bsize[i] = 0;
    const void* ps[4] = { user, ent, vals, W };
    int k = t >> 5, i = t & 31;
    float v = ((const float*)ps[k])[i];
    int ok = (v == v && fabsf(v) <= 1e4f) ? 1 : 0;
    ok += __shfl_xor(ok, 1, 64);
    ok += __shfl_xor(ok, 2, 64);
    ok += __shfl_xor(ok, 4, 64);
    ok += __shfl_xor(ok, 8, 64);
    ok += __shfl_xor(ok, 16, 64);   // xor<32: reduction stays within 32-lane half
    if ((t & 31) == 0) flags[k] = (ok >= 16) ? 1 : 0;
}

// ---------------------------------------------------------------------------
// Pass A: per-block LDS histogram over NB coarse buckets (bucket = row>>8).
// Zero global atomic contention (LDS atomics only); per-bucket totals via
// 196*391 low-contention global atomics.
// ---------------------------------------------------------------------------
__global__ __launch_bounds__(256) void k_hista(const int* __restrict__ rows,
                                               int* __restrict__ cnt_table,
                                               int* __restrict__ bsize) {
    __shared__ int h[NB];
    int t = threadIdx.x, blk = blockIdx.x;
    for (int b = t; b < NB; b += 256) h[b] = 0;
    __syncthreads();
    int base = blk * CHUNK + t * 4;
#pragma unroll
    for (int it = 0; it < 8; ++it) {
        int e = base + it * 1024;
        if (e < N_EDGES) {
            int4 r = *(const int4*)&rows[e];
            atomicAdd(&h[r.x >> 8], 1);
            atomicAdd(&h[r.y >> 8], 1);
            atomicAdd(&h[r.z >> 8], 1);
            atomicAdd(&h[r.w >> 8], 1);
        }
    }
    __syncthreads();
    for (int b = t; b < NB; b += 256) {
        int v = h[b];
        cnt_table[blk * NB + b] = v;           // [block][bucket], contiguous write
        if (v) atomicAdd(&bsize[b], v);
    }
}

// exclusive scan of padded bucket allocations -> bbase[0..NB]
__global__ __launch_bounds__(512) void k_bscan(const int* __restrict__ bsize,
                                               int* __restrict__ bbase) {
    __shared__ int lds[512];
    int t = threadIdx.x;
    // alloc = round4(bsize) + BUCK_SLACK (covers group-max padding overhead)
    int v = (t < NB) ? (((bsize[t] + 3) & ~3) + BUCK_SLACK) : 0;
    lds[t] = v;
    __syncthreads();
    for (int off = 1; off < 512; off <<= 1) {
        int u = (t >= off) ? lds[t - off] : 0;
        __syncthreads();
        lds[t] += u;
        __syncthreads();
    }
    if (t <= NB) bbase[t] = (t == 0) ? 0 : lds[t - 1];
}

// per-bucket scan over blocks: cnt_table[blk][b] -> bbase[b] + excl prefix
__global__ __launch_bounds__(256) void k_bscan2(int* __restrict__ cnt_table,
                                                const int* __restrict__ bbase) {
    __shared__ int lds[256];
    int t = threadIdx.x, b = blockIdx.x;
    int v = (t < NBLK_B) ? cnt_table[t * NB + b] : 0;
    lds[t] = v;
    __syncthreads();
    for (int off = 1; off < 256; off <<= 1) {
        int u = (t >= off) ? lds[t - off] : 0;
        __syncthreads();
        lds[t] += u;
        __syncthreads();
    }
    if (t < NBLK_B) cnt_table[t * NB + b] = bbase[b] + lds[t] - v;  // exclusive
}

// ---------------------------------------------------------------------------
// Pass B: stable-ish scatter into bucket order. Each block owns exact
// pre-reserved sub-regions per bucket (from cnt_table), cursors live in LDS
// -> zero global atomics; writes are contiguous runs per (block,bucket).
// Payload: col(17b) | row-in-bucket(8b)<<17, val bits.
// ---------------------------------------------------------------------------
__global__ __launch_bounds__(256) void k_bscatter2(
    const int* __restrict__ rows, const int* __restrict__ cols,
    const void* __restrict__ vals, const int* __restrict__ cnt_table,
    int2* __restrict__ bpack, const int* __restrict__ flags) {
    __shared__ int cur[NB];
    int t = threadIdx.x, blk = blockIdx.x;
    int fv = flags[2];
    for (int b = t; b < NB; b += 256) cur[b] = cnt_table[blk * NB + b];
    __syncthreads();
    int base = blk * CHUNK + t * 4;
#pragma unroll
    for (int it = 0; it < 8; ++it) {
        int e = base + it * 1024;
        if (e < N_EDGES) {
            int4 r = *(const int4*)&rows[e];
            int4 c = *(const int4*)&cols[e];
            float v0, v1, v2, v3;
            if (fv) {
                float4 vv = *(const float4*)((const float*)vals + e);
                v0 = vv.x; v1 = vv.y; v2 = vv.z; v3 = vv.w;
            } else {
                const bf16* bp = (const bf16*)vals + e;
                v0 = b2f(bp[0]); v1 = b2f(bp[1]); v2 = b2f(bp[2]); v3 = b2f(bp[3]);
            }
            int p0 = atomicAdd(&cur[r.x >> 8], 1);
            int p1 = atomicAdd(&cur[r.y >> 8], 1);
            int p2 = atomicAdd(&cur[r.z >> 8], 1);
            int p3 = atomicAdd(&cur[r.w >> 8], 1);
            bpack[p0] = make_int2(c.x | ((r.x & 255) << 17), __float_as_int(v0));
            bpack[p1] = make_int2(c.y | ((r.y & 255) << 17), __float_as_int(v1));
            bpack[p2] = make_int2(c.z | ((r.z & 255) << 17), __float_as_int(v2));
            bpack[p3] = make_int2(c.w | ((r.w & 255) << 17), __float_as_int(v3));
        }
    }
}

// ---------------------------------------------------------------------------
// Pass C: one block per bucket. Stage bucket edges in LDS + row histogram,
// GROUP-MAX padding: each 4-row group (one gather wave's rows) is padded so
// all 4 rows share the same slot count -> the gather loop needs no masks and
// a uniform trip count. Pad slots are (col=0, val=0). Scan padded counts ->
// row_start/row_end, place edges via LDS cursors, zero-fill pads.
// ---------------------------------------------------------------------------
__global__ __launch_bounds__(256) void k_place2(
    const int* __restrict__ bsize, const int* __restrict__ bbase,
    const int2* __restrict__ bpack, int2* __restrict__ epack,
    int* __restrict__ row_start, int* __restrict__ row_end) {
    __shared__ __align__(16) int2 stage[STAGE_CAP];
    __shared__ int rcnt[ROWS_PER_BUCK];
    __shared__ int scan_lds[ROWS_PER_BUCK];
    __shared__ int rstart[ROWS_PER_BUCK];
    __shared__ int cur[ROWS_PER_BUCK];
    int t = threadIdx.x, b = blockIdx.x;
    int n = bsize[b];
    int gstart = bbase[b];
    rcnt[t] = 0;
    __syncthreads();
    for (int i = t; i < n; i += 256) {
        int2 p = bpack[gstart + i];
        if (i < STAGE_CAP) stage[i] = p;
        atomicAdd(&rcnt[(p.x >> 17) & 255], 1);
    }
    __syncthreads();
    int c = rcnt[t];
    int cp = (c + 3) & ~3;                 // pad row to multiple of 4 edges
    int g = cp;                            // group-of-4 max (one wave's rows)
    g = max(g, __shfl_xor(g, 1, 64));
    g = max(g, __shfl_xor(g, 2, 64));
    scan_lds[t] = g;
    __syncthreads();
    for (int off = 1; off < 256; off <<= 1) {
        int u = (t >= off) ? scan_lds[t - off] : 0;
        __syncthreads();
        scan_lds[t] += u;
        __syncthreads();
    }
    int rs_ = gstart + scan_lds[t] - g;    // exclusive
    rstart[t] = rs_;
    cur[t] = rs_;
    int node = b * ROWS_PER_BUCK + t;
    if (node < N_NODES) {
        row_start[node] = rs_;
        row_end[node] = rs_ + g;
    }
    __syncthreads();
    for (int i = t; i < n; i += 256) {
        int2 p = (i < STAGE_CAP) ? stage[i] : bpack[gstart + i];
        int r = (p.x >> 17) & 255;
        int pos = atomicAdd(&cur[r], 1);
        epack[pos] = make_int2(p.x & 0x1FFFF, p.y);
    }
    __syncthreads();
    int pend = rstart[t] + g;
    for (int pos = cur[t]; pos < pend; ++pos) epack[pos] = make_int2(0, 0);
}

// ---------------------------------------------------------------------------
// out[:, :64] = concat(user, entity); xb0 = bf16 gather table of ego0
// ---------------------------------------------------------------------------
__global__ void k_init(const void* __restrict__ user, const void* __restrict__ ent,
                       void* __restrict__ out, bf16* __restrict__ xb0,
                       const int* __restrict__ flags) {
    int i = blockIdx.x * blockDim.x + threadIdx.x;
    if (i >= N_NODES * DIM) return;
    int fo = flags[0], fe = flags[1];
    int n = i >> 6, d = i & 63;
    float v = (n < N_USERS) ? ld(user, i, fo) : ld(ent, i - N_USERS * DIM, fe);
    st(out, n * 160 + d, v, fo);
    xb0[i] = f2b(v);
}

// ---------------------------------------------------------------------------
// Gather phase (shared by both layers): wave owns 4 rows (one padded group,
// all rows the same length), lane = dim. Mask-free: pad slots are real
// (col=0,val=0) edges; trip count is wave-uniform (scalar loop). 16 gathers
// in flight per iter; next quads prefetched between issue and FMA.
// ---------------------------------------------------------------------------
#define GATHER_ROW_DECL(r) \
    int ej##r = rs[r] >> 1; \
    int4 eA##r = ep4[ej##r]; \
    int4 eB##r = ep4[ej##r + 1]; \
    float ea##r = 0.f;

#define GATHER_ISSUE(r) \
    unsigned eg##r##0 = xu[eA##r.x * 64 + lane]; \
    unsigned eg##r##1 = xu[eA##r.z * 64 + lane]; \
    unsigned eg##r##2 = xu[eB##r.x * 64 + lane]; \
    unsigned eg##r##3 = xu[eB##r.z * 64 + lane];

#define GATHER_ADV(r) \
    int4 nA##r = ep4[ej##r + 2]; \
    int4 nB##r = ep4[ej##r + 3]; \
    ej##r += 2;

#define GATHER_FMA(r) \
    ea##r += __int_as_float(eA##r.y) * ubf(eg##r##0); \
    ea##r += __int_as_float(eA##r.w) * ubf(eg##r##1); \
    ea##r += __int_as_float(eB##r.y) * ubf(eg##r##2); \
    ea##r += __int_as_float(eB##r.w) * ubf(eg##r##3); \
    eA##r = nA##r; eB##r = nB##r;

#define GATHER_BODY(EMX) \
    GATHER_ROW_DECL(0) GATHER_ROW_DECL(1) GATHER_ROW_DECL(2) GATHER_ROW_DECL(3) \
    for (int ei = 0; ei < (EMX); ei += 4) { \
        GATHER_ISSUE(0) GATHER_ISSUE(1) GATHER_ISSUE(2) GATHER_ISSUE(3) \
        GATHER_ADV(0) GATHER_ADV(1) GATHER_ADV(2) GATHER_ADV(3) \
        GATHER_FMA(0) GATHER_FMA(1) GATHER_FMA(2) GATHER_FMA(3) \
    }

// ---------------------------------------------------------------------------
// Fused layer 1 (64->64): 16 rows/block, 4 waves. MFMA combine, C/D layout
// col=lane&15, row=(lane>>4)*4+reg. Wave w -> output cols 16w..16w+15.
// ---------------------------------------------------------------------------
__global__ __launch_bounds__(256) void k_layer1(
    const void* __restrict__ W1, const void* __restrict__ b1,
    const void* __restrict__ W2, const void* __restrict__ b2,
    void* __restrict__ out, const int* __restrict__ row_start,
    const int* __restrict__ row_end,
    const int2* __restrict__ epack, const bf16* __restrict__ xt,
    bf16* __restrict__ xn, const int* __restrict__ flags) {
    __shared__ __align__(16) unsigned short hp_lds[16][72];
    __shared__ __align__(16) unsigned short hm_lds[16][72];
    __shared__ __align__(16) float ssq_lds[16][4];
    int t = threadIdx.x, lane = t & 63, w = t >> 6;
    int sub = lane & 15, quad = lane >> 4;
    int fo = flags[0], fw = flags[3];
    int rbase = blockIdx.x * 16 + w * 4;
    const unsigned short* xu = (const unsigned short*)xt;
    const int4* ep4 = (const int4*)epack;

    int4 rsv = *(const int4*)&row_start[rbase];
    int rs[4] = { rsv.x, rsv.y, rsv.z, rsv.w };
    int emx = __builtin_amdgcn_readfirstlane(row_end[rbase] - rsv.x);
    GATHER_BODY(emx)
    {
        float s[4] = { ea0, ea1, ea2, ea3 };
#pragma unroll
        for (int r = 0; r < 4; ++r) {
            float h = ld(out, (rbase + r) * 160 + lane, fo);
            hp_lds[w * 4 + r][lane] = fbits(h + s[r]);
            hm_lds[w * 4 + r][lane] = fbits(h * s[r]);
        }
    }
    __syncthreads();

    // A fragments: A[m=sub][k=quad*8+j] (+32 for second k-half)
    short8 Ap0 = *(const short8*)((const char*)hp_lds + sub * 144 + quad * 16);
    short8 Ap1 = *(const short8*)((const char*)hp_lds + sub * 144 + 64 + quad * 16);
    short8 Am0 = *(const short8*)((const char*)hm_lds + sub * 144 + quad * 16);
    short8 Am1 = *(const short8*)((const char*)hm_lds + sub * 144 + 64 + quad * 16);

    // B fragments: B[k=quad*8+j][n=wbase+sub], W row-major [64][64]
    int wbase = w * 16;
    short8 Bw10, Bw11, Bw20, Bw21;
    float bias1, bias2;
    if (fw) {
        const float* w1 = (const float*)W1;
        const float* w2 = (const float*)W2;
#pragma unroll
        for (int j = 0; j < 8; ++j) {
            int k0 = quad * 8 + j;
            Bw10[j] = (short)fbits(w1[k0 * 64 + wbase + sub]);
            Bw11[j] = (short)fbits(w1[(k0 + 32) * 64 + wbase + sub]);
            Bw20[j] = (short)fbits(w2[k0 * 64 + wbase + sub]);
            Bw21[j] = (short)fbits(w2[(k0 + 32) * 64 + wbase + sub]);
        }
        bias1 = ((const float*)b1)[wbase + sub];
        bias2 = ((const float*)b2)[wbase + sub];
    } else {
        const unsigned short* w1 = (const unsigned short*)W1;
        const unsigned short* w2 = (const unsigned short*)W2;
#pragma unroll
        for (int j = 0; j < 8; ++j) {
            int k0 = quad * 8 + j;
            Bw10[j] = (short)w1[k0 * 64 + wbase + sub];
            Bw11[j] = (short)w1[(k0 + 32) * 64 + wbase + sub];
            Bw20[j] = (short)w2[k0 * 64 + wbase + sub];
            Bw21[j] = (short)w2[(k0 + 32) * 64 + wbase + sub];
        }
        bias1 = b2f(((const bf16*)b1)[wbase + sub]);
        bias2 = b2f(((const bf16*)b2)[wbase + sub]);
    }

    floatx4 c1; c1[0] = bias1; c1[1] = bias1; c1[2] = bias1; c1[3] = bias1;
    floatx4 c2; c2[0] = bias2; c2[1] = bias2; c2[2] = bias2; c2[3] = bias2;
    c1 = __builtin_amdgcn_mfma_f32_16x16x32_bf16(Ap0, Bw10, c1, 0, 0, 0);
    c1 = __builtin_amdgcn_mfma_f32_16x16x32_bf16(Ap1, Bw11, c1, 0, 0, 0);
    c2 = __builtin_amdgcn_mfma_f32_16x16x32_bf16(Am0, Bw20, c2, 0, 0, 0);
    c2 = __builtin_amdgcn_mfma_f32_16x16x32_bf16(Am1, Bw21, c2, 0, 0, 0);

    float v[4], sp[4];
#pragma unroll
    for (int r = 0; r < 4; ++r) {
        float s1 = c1[r], s2 = c2[r];
        s1 = s1 > 0.f ? s1 : 0.01f * s1;
        s2 = s2 > 0.f ? s2 : 0.01f * s2;
        v[r] = s1 + s2;
        float sq = v[r] * v[r];
        sq += __shfl_xor(sq, 1, 64);
        sq += __shfl_xor(sq, 2, 64);
        sq += __shfl_xor(sq, 4, 64);
        sq += __shfl_xor(sq, 8, 64);
        sp[r] = sq;
    }
    if (sub == 0) {
#pragma unroll
        for (int r = 0; r < 4; ++r) ssq_lds[quad * 4 + r][w] = sp[r];
    }
    __syncthreads();
#pragma unroll
    for (int r = 0; r < 4; ++r) {
        int row = quad * 4 + r;
        floatx4 ps = *(const floatx4*)&ssq_lds[row][0];
        float ss = ps[0] + ps[1] + ps[2] + ps[3];
        float o = v[r] * (1.0f / fmaxf(sqrtf(ss), 1e-12f));
        int n = blockIdx.x * 16 + row;
        st(out, n * 160 + 64 + wbase + sub, o, fo);
        xn[n * 64 + wbase + sub] = f2b(o);
    }
}

// ---------------------------------------------------------------------------
// Fused layer 2 (64->32): same gather; waves 0,1 = sum path (W1), waves 2,3 =
// bi path (W2); cross-path add via LDS; l2norm over 32.
// ---------------------------------------------------------------------------
__global__ __launch_bounds__(256) void k_layer2(
    const void* __restrict__ W1, const void* __restrict__ b1,
    const void* __restrict__ W2, const void* __restrict__ b2,
    void* __restrict__ out, const int* __restrict__ row_start,
    const int* __restrict__ row_end,
    const int2* __restrict__ epack, const bf16* __restrict__ xt,
    const int* __restrict__ flags) {
    __shared__ __align__(16) unsigned short hp_lds[16][72];
    __shared__ __align__(16) unsigned short hm_lds[16][72];
    __shared__ __align__(16) float bi_lds[16][32];
    __shared__ __align__(16) float ssq_lds[16][2];
    int t = threadIdx.x, lane = t & 63, w = t >> 6;
    int sub = lane & 15, quad = lane >> 4;
    int fo = flags[0], fw = flags[3];
    int rbase = blockIdx.x * 16 + w * 4;
    const unsigned short* xu = (const unsigned short*)xt;
    const int4* ep4 = (const int4*)epack;

    int4 rsv = *(const int4*)&row_start[rbase];
    int rs[4] = { rsv.x, rsv.y, rsv.z, rsv.w };
    int emx = __builtin_amdgcn_readfirstlane(row_end[rbase] - rsv.x);
    GATHER_BODY(emx)
    {
        float s[4] = { ea0, ea1, ea2, ea3 };
#pragma unroll
        for (int r = 0; r < 4; ++r) {
            float h = ld(out, (rbase + r) * 160 + 64 + lane, fo);
            hp_lds[w * 4 + r][lane] = fbits(h + s[r]);
            hm_lds[w * 4 + r][lane] = fbits(h * s[r]);
        }
    }
    __syncthreads();

    int path = w >> 1;               // 0: sum(W1), 1: bi(W2)
    int nbase = (w & 1) * 16;        // col tile within 32
    const unsigned short(*hl)[72] = path ? hm_lds : hp_lds;
    short8 Af0 = *(const short8*)((const char*)hl + sub * 144 + quad * 16);
    short8 Af1 = *(const short8*)((const char*)hl + sub * 144 + 64 + quad * 16);

    const void* W = path ? W2 : W1;
    const void* bb = path ? b2 : b1;
    short8 Bf0, Bf1;
    float bias;
    if (fw) {
        const float* wp = (const float*)W;
#pragma unroll
        for (int j = 0; j < 8; ++j) {
            int k0 = quad * 8 + j;
            Bf0[j] = (short)fbits(wp[k0 * 32 + nbase + sub]);
            Bf1[j] = (short)fbits(wp[(k0 + 32) * 32 + nbase + sub]);
        }
        bias = ((const float*)bb)[nbase + sub];
    } else {
        const unsigned short* wp = (const unsigned short*)W;
#pragma unroll
        for (int j = 0; j < 8; ++j) {
            int k0 = quad * 8 + j;
            Bf0[j] = (short)wp[k0 * 32 + nbase + sub];
            Bf1[j] = (short)wp[(k0 + 32) * 32 + nbase + sub];
        }
        bias = b2f(((const bf16*)bb)[nbase + sub]);
    }

    floatx4 c; c[0] = bias; c[1] = bias; c[2] = bias; c[3] = bias;
    c = __builtin_amdgcn_mfma_f32_16x16x32_bf16(Af0, Bf0, c, 0, 0, 0);
    c = __builtin_amdgcn_mfma_f32_16x16x32_bf16(Af1, Bf1, c, 0, 0, 0);

    float T[4];
#pragma unroll
    for (int r = 0; r < 4; ++r) {
        float x = c[r];
        T[r] = x > 0.f ? x : 0.01f * x;
        if (path == 1) bi_lds[quad * 4 + r][nbase + sub] = T[r];
    }
    __syncthreads();

    float v[4], sp[4];
#pragma unroll
    for (int r = 0; r < 4; ++r) {
        v[r] = T[r] + bi_lds[quad * 4 + r][nbase + sub];
        float sq = v[r] * v[r];
        sq += __shfl_xor(sq, 1, 64);
        sq += __shfl_xor(sq, 2, 64);
        sq += __shfl_xor(sq, 4, 64);
        sq += __shfl_xor(sq, 8, 64);
        sp[r] = sq;
    }
    if (path == 0 && sub == 0) {
#pragma unroll
        for (int r = 0; r < 4; ++r) ssq_lds[quad * 4 + r][w & 1] = sp[r];
    }
    __syncthreads();
    if (path == 0) {
#pragma unroll
        for (int r = 0; r < 4; ++r) {
            int row = quad * 4 + r;
            float ss = ssq_lds[row][0] + ssq_lds[row][1];
            float o = v[r] * (1.0f / fmaxf(sqrtf(ss), 1e-12f));
            int n = blockIdx.x * 16 + row;
            st(out, n * 160 + 128 + nbase + sub, o, fo);
        }
    }
}

extern "C" void kernel_launch(void* const* d_in, const int* in_sizes, int n_in,
                              void* d_out, int out_size, void* d_ws, size_t ws_size,
                              hipStream_t stream) {
    const void* user = d_in[0];
    const void* ent  = d_in[1];
    const void* vals = d_in[2];
    const void* W1_1 = d_in[3];
    const void* b1_1 = d_in[4];
    const void* W2_1 = d_in[5];
    const void* b2_1 = d_in[6];
    const void* W1_2 = d_in[7];
    const void* b1_2 = d_in[8];
    const void* W2_2 = d_in[9];
    const void* b2_2 = d_in[10];
    const int* rows  = (const int*)d_in[11];
    const int* cols  = (const int*)d_in[12];

    // ws layout: [flags][bsize][bbase][row_start][row_end][epack][xb0][xb1]
    // cnt_table aliases epack (dead once k_bscatter2 completes, before k_place2
    // writes epack); bpack aliases xb0+xb1 (dead before k_init writes xb0).
    char* w = (char*)d_ws;
    int* flags     = (int*)w;  w += 256;
    int* bsize     = (int*)w;  w += 2048;                    // NB ints
    int* bbase     = (int*)w;  w += 2048;                    // NB+1 ints
    int* row_start = (int*)w;  w += 400128;                  // N_NODES ints padded
    int* row_end   = (int*)w;  w += 400128;
    int2* epack    = (int2*)w; w += (size_t)E_ALLOC * 8;
    bf16* xb0      = (bf16*)w; w += (size_t)N_NODES * DIM * 2;
    bf16* xb1      = (bf16*)w;
    int* cnt_table = (int*)epack;   // NBLK_B*NB ints = 307 KB << epack
    int2* bpack    = (int2*)xb0;    // 12.8 MB <= 25.6 MB of xb0+xb1

    k_detect<<<1, 128, 0, stream>>>(user, ent, vals, W1_1, flags, bsize);
    k_hista<<<NBLK_B, 256, 0, stream>>>(rows, cnt_table, bsize);
    k_bscan<<<1, 512, 0, stream>>>(bsize, bbase);
    k_bscan2<<<NB, 256, 0, stream>>>(cnt_table, bbase);
    k_bscatter2<<<NBLK_B, 256, 0, stream>>>(rows, cols, vals, cnt_table, bpack, flags);
    k_place2<<<NB, 256, 0, stream>>>(bsize, bbase, bpack, epack, row_start, row_end);
    k_init<<<(N_NODES * DIM + 255) / 256, 256, 0, stream>>>(user, ent, d_out, xb0, flags);
    k_layer1<<<N_NODES / 16, 256, 0, stream>>>(W1_1, b1_1, W2_1, b2_1, d_out, row_start, row_end, epack, xb0, xb1, flags);
    k_layer2<<<N_NODES / 16, 256, 0, stream>>>(W1_2, b1_2, W2_2, b2_2, d_out, row_start, row_end, epack, xb1, flags);
}